// Round 3
// baseline (290.931 us; speedup 1.0000x reference)
//
#include <hip/hip_runtime.h>
#include <cstdint>
#include <cstddef>

#define WS 64
#define SHIFT 32
#define WTOT 8192
#define NWIN 128
#define NWPB 8          // windows per block
#define NBLK 512        // NWPB * NBLK = 4096 windows
#define SCALE_F 0.125f

typedef __bf16 bf16x8 __attribute__((ext_vector_type(8)));
typedef __bf16 bf16x4 __attribute__((ext_vector_type(4)));
typedef float f32x4 __attribute__((ext_vector_type(4)));

// u16-unit swizzle for [64][64]-u16 tiles; conflict-free for every access
// pattern in this kernel (validated R1: conflicts 13.1M -> 2.1M).
__device__ __forceinline__ int swz16(int row, int col) {
  return (row * WS + col) ^ (((row >> 1) & 7) << 3);
}

// One block = 8 windows, software-pipelined: window w+1's global loads are
// issued before window w's compute, so load latency hides under MFMA/softmax.
// LDS = 2 slots x 32 KiB (K hi/lo + V^T hi/lo) = 64 KiB -> 2 blocks/CU.
__global__ __launch_bounds__(256, 2) void win_attn(
    const float* __restrict__ q, const float* __restrict__ k,
    const float* __restrict__ v, const float* __restrict__ table,
    float* __restrict__ xout, float* __restrict__ attn_out) {
  __shared__ __align__(16) unsigned short s_mem[2][4 * WS * WS];  // 2 x 32 KiB

  const int t = threadIdx.x;
  const int bid = blockIdx.x;
  const int lane = t & 63;
  const int wave = t >> 6;        // 0..3 -> rows [16w,16w+16)
  const int lrow = lane & 15;
  const int quad = lane >> 4;

  // staging coordinates
  const int klr = t >> 2;         // K row 0..63
  const int klc = (t & 3) << 4;   // K col base 0,16,32,48
  const int vm0 = (t >> 4) << 2;  // V source rows m0..m0+3
  const int vc0 = (t & 15) << 2;  // V cols c0..c0+3

  // relative-position bias (mask applied per-window in softmax)
  float biasr[4][4];
  {
    const float* tb = table + (WS - 1);
#pragma unroll
    for (int reg = 0; reg < 4; ++reg) {
      const int r = wave * 16 + quad * 4 + reg;
#pragma unroll
      for (int j = 0; j < 4; ++j) {
        biasr[reg][j] = __ldg(tb + (r - (j * 16 + lrow)));
      }
    }
  }

  float4 L[2][12];  // [parity][0..3 Q | 4..7 K | 8..11 V] — all indices
                    // compile-time constant after full unroll (rule #20)

#define ISSUE(W)                                                          \
  {                                                                       \
    const int wid_ = bid * NWPB + (W);                                    \
    const int ba_ = wid_ >> 7;                                            \
    const int wi_ = wid_ & (NWIN - 1);                                    \
    const size_t base_ = (size_t)ba_ * WTOT;                              \
    const int qr_ = (wi_ * WS + wave * 16 + lrow + SHIFT) & (WTOT - 1);   \
    const float* qp_ = q + (base_ + qr_) * WS + quad * 8;                 \
    L[(W) & 1][0] = *(const float4*)(qp_);                                \
    L[(W) & 1][1] = *(const float4*)(qp_ + 4);                            \
    L[(W) & 1][2] = *(const float4*)(qp_ + 32);                           \
    L[(W) & 1][3] = *(const float4*)(qp_ + 36);                           \
    const int kr_ = (wi_ * WS + klr + SHIFT) & (WTOT - 1);                \
    const float* kp_ = k + (base_ + kr_) * WS + klc;                      \
    L[(W) & 1][4] = *(const float4*)(kp_);                                \
    L[(W) & 1][5] = *(const float4*)(kp_ + 4);                            \
    L[(W) & 1][6] = *(const float4*)(kp_ + 8);                            \
    L[(W) & 1][7] = *(const float4*)(kp_ + 12);                           \
    const int vr0_ = (wi_ * WS + vm0 + 0 + SHIFT) & (WTOT - 1);           \
    const int vr1_ = (wi_ * WS + vm0 + 1 + SHIFT) & (WTOT - 1);           \
    const int vr2_ = (wi_ * WS + vm0 + 2 + SHIFT) & (WTOT - 1);           \
    const int vr3_ = (wi_ * WS + vm0 + 3 + SHIFT) & (WTOT - 1);           \
    L[(W) & 1][8]  = *(const float4*)(v + (base_ + vr0_) * WS + vc0);     \
    L[(W) & 1][9]  = *(const float4*)(v + (base_ + vr1_) * WS + vc0);     \
    L[(W) & 1][10] = *(const float4*)(v + (base_ + vr2_) * WS + vc0);     \
    L[(W) & 1][11] = *(const float4*)(v + (base_ + vr3_) * WS + vc0);     \
  }

  ISSUE(0);

#pragma unroll
  for (int w = 0; w < NWPB; ++w) {
    const int s = w & 1;
    unsigned short* const s_khi  = s_mem[s];                 // later P_hi
    unsigned short* const s_klo  = s_mem[s] + WS * WS;       // later P_lo
    unsigned short* const s_vthi = s_mem[s] + 2 * WS * WS;   // V^T [c][m]
    unsigned short* const s_vtlo = s_mem[s] + 3 * WS * WS;

    const int wid = bid * NWPB + w;
    const int batch = wid >> 7;
    const int win = wid & (NWIN - 1);
    const bool masked = (win == NWIN - 1);
    const size_t base = (size_t)batch * WTOT;

    // prefetch next window while this one computes (T14)
    if (w + 1 < NWPB) ISSUE(w + 1);

    // ---- stage K -> hi/lo bf16, b128 swizzled writes ----
    {
      const float a[16] = {L[s][4].x, L[s][4].y, L[s][4].z, L[s][4].w,
                           L[s][5].x, L[s][5].y, L[s][5].z, L[s][5].w,
                           L[s][6].x, L[s][6].y, L[s][6].z, L[s][6].w,
                           L[s][7].x, L[s][7].y, L[s][7].z, L[s][7].w};
#pragma unroll
      for (int h = 0; h < 2; ++h) {
        bf16x8 hv, lv;
#pragma unroll
        for (int e = 0; e < 8; ++e) {
          const float x = a[8 * h + e];
          const __bf16 hh = (__bf16)x;
          hv[e] = hh;
          lv[e] = (__bf16)(x - (float)hh);
        }
        const int idx = swz16(klr, klc + 8 * h);
        *(bf16x8*)(s_khi + idx) = hv;
        *(bf16x8*)(s_klo + idx) = lv;
      }
    }
    // ---- stage V^T: 4x4 register micro-transpose, b64 swizzled writes ----
    {
      const float vb[4][4] = {
          {L[s][8].x,  L[s][8].y,  L[s][8].z,  L[s][8].w},
          {L[s][9].x,  L[s][9].y,  L[s][9].z,  L[s][9].w},
          {L[s][10].x, L[s][10].y, L[s][10].z, L[s][10].w},
          {L[s][11].x, L[s][11].y, L[s][11].z, L[s][11].w}};
#pragma unroll
      for (int e = 0; e < 4; ++e) {
        bf16x4 hv, lv;
#pragma unroll
        for (int j = 0; j < 4; ++j) {
          const float x = vb[j][e];
          const __bf16 hh = (__bf16)x;
          hv[j] = hh;
          lv[j] = (__bf16)(x - (float)hh);
        }
        const int idx = swz16(vc0 + e, vm0);
        *(bf16x4*)(s_vthi + idx) = hv;
        *(bf16x4*)(s_vtlo + idx) = lv;
      }
    }
    // ---- Q fragments (wave-private rows; never touch LDS) ----
    bf16x8 qfhi[2], qflo[2];
#pragma unroll
    for (int kh = 0; kh < 2; ++kh) {
      const float a[8] = {L[s][2 * kh].x,     L[s][2 * kh].y,
                          L[s][2 * kh].z,     L[s][2 * kh].w,
                          L[s][2 * kh + 1].x, L[s][2 * kh + 1].y,
                          L[s][2 * kh + 1].z, L[s][2 * kh + 1].w};
      bf16x8 hv, lv;
#pragma unroll
      for (int e = 0; e < 8; ++e) {
        const __bf16 hh = (__bf16)a[e];
        hv[e] = hh;
        lv[e] = (__bf16)(a[e] - (float)hh);
      }
      qfhi[kh] = hv;
      qflo[kh] = lv;
    }

    __syncthreads();  // (a) K, V^T visible

    // ---- S = Q K^T via split-bf16 MFMA ----
    const f32x4 z4 = {0.f, 0.f, 0.f, 0.f};
    f32x4 acc[4] = {z4, z4, z4, z4};
#pragma unroll
    for (int kh = 0; kh < 2; ++kh) {
      const int k0 = kh * 32 + quad * 8;
      const bf16x8 ahi = qfhi[kh];
      const bf16x8 alo = qflo[kh];
#pragma unroll
      for (int j = 0; j < 4; ++j) {
        const int idx = swz16(j * 16 + lrow, k0);
        const bf16x8 bhi = *(const bf16x8*)(s_khi + idx);
        const bf16x8 blo = *(const bf16x8*)(s_klo + idx);
        acc[j] = __builtin_amdgcn_mfma_f32_16x16x32_bf16(ahi, bhi, acc[j], 0, 0, 0);
        acc[j] = __builtin_amdgcn_mfma_f32_16x16x32_bf16(alo, bhi, acc[j], 0, 0, 0);
        acc[j] = __builtin_amdgcn_mfma_f32_16x16x32_bf16(ahi, blo, acc[j], 0, 0, 0);
      }
    }

    // ---- register softmax (row split across 16 lanes of a quad) ----
    float p[4][4];
#pragma unroll
    for (int reg = 0; reg < 4; ++reg) {
      const int r = wave * 16 + quad * 4 + reg;
      float val[4];
      float vmax = -1e30f;
#pragma unroll
      for (int j = 0; j < 4; ++j) {
        const int m = j * 16 + lrow;
        float sv = acc[j][reg] * SCALE_F + biasr[reg][j];
        if (masked && (((r ^ m) & 32) != 0)) sv -= 100.0f;
        val[j] = sv;
        vmax = fmaxf(vmax, sv);
      }
#pragma unroll
      for (int off = 1; off < 16; off <<= 1)
        vmax = fmaxf(vmax, __shfl_xor(vmax, off, 64));
      float sum = 0.f;
#pragma unroll
      for (int j = 0; j < 4; ++j) {
        val[j] = __expf(val[j] - vmax);
        sum += val[j];
      }
#pragma unroll
      for (int off = 1; off < 16; off <<= 1)
        sum += __shfl_xor(sum, off, 64);
      const float inv = 1.0f / sum;
#pragma unroll
      for (int j = 0; j < 4; ++j) p[reg][j] = val[j] * inv;
    }

    __syncthreads();  // (b) all K-fragment reads done -> K buffers reusable for P

    // ---- write attn (direct), stage P hi/lo into freed K buffers ----
    {
      float* arow = attn_out + (size_t)wid * (WS * WS);
#pragma unroll
      for (int reg = 0; reg < 4; ++reg) {
        const int r = wave * 16 + quad * 4 + reg;
#pragma unroll
        for (int j = 0; j < 4; ++j) {
          const int m = j * 16 + lrow;
          const float pv = p[reg][j];
          arow[r * WS + m] = pv;
          const __bf16 hh = (__bf16)pv;
          const int idx = swz16(r, m);
          *(__bf16*)(s_khi + idx) = hh;
          *(__bf16*)(s_klo + idx) = (__bf16)(pv - (float)hh);
        }
      }
    }
    __syncthreads();  // (c) P visible

    // ---- X = P V via split-bf16 MFMA ----
    f32x4 xacc[4] = {z4, z4, z4, z4};
#pragma unroll
    for (int kh = 0; kh < 2; ++kh) {
      const int k0 = kh * 32 + quad * 8;
      const int aidx = swz16(wave * 16 + lrow, k0);
      const bf16x8 phi = *(const bf16x8*)(s_khi + aidx);
      const bf16x8 plo = *(const bf16x8*)(s_klo + aidx);
#pragma unroll
      for (int j = 0; j < 4; ++j) {
        const int idx = swz16(j * 16 + lrow, k0);
        const bf16x8 vhi = *(const bf16x8*)(s_vthi + idx);
        const bf16x8 vlo = *(const bf16x8*)(s_vtlo + idx);
        xacc[j] = __builtin_amdgcn_mfma_f32_16x16x32_bf16(phi, vhi, xacc[j], 0, 0, 0);
        xacc[j] = __builtin_amdgcn_mfma_f32_16x16x32_bf16(plo, vhi, xacc[j], 0, 0, 0);
        xacc[j] = __builtin_amdgcn_mfma_f32_16x16x32_bf16(phi, vlo, xacc[j], 0, 0, 0);
      }
    }

    // ---- store x with reverse cyclic shift ----
#pragma unroll
    for (int reg = 0; reg < 4; ++reg) {
      const int r = wave * 16 + quad * 4 + reg;
      const int gr = (win * WS + r + SHIFT) & (WTOT - 1);
      float* xrow = xout + (base + gr) * WS;
#pragma unroll
      for (int j = 0; j < 4; ++j) {
        xrow[j * 16 + lrow] = xacc[j][reg];
      }
    }
  }
#undef ISSUE
}

extern "C" void kernel_launch(void* const* d_in, const int* in_sizes, int n_in,
                              void* d_out, int out_size, void* d_ws, size_t ws_size,
                              hipStream_t stream) {
  (void)in_sizes; (void)n_in; (void)out_size; (void)d_ws; (void)ws_size;
  const float* q = (const float*)d_in[0];
  const float* k = (const float*)d_in[1];
  const float* v = (const float*)d_in[2];
  const float* table = (const float*)d_in[3];
  float* xout = (float*)d_out;                               // (32, 8192, 64)
  float* attn = (float*)d_out + (size_t)32 * WTOT * WS;      // (4096, 64, 64)
  win_attn<<<dim3(NBLK), dim3(256), 0, stream>>>(q, k, v, table, xout, attn);
}